// Round 9
// baseline (139.062 us; speedup 1.0000x reference)
//
#include <hip/hip_runtime.h>

#define ZD   128
#define NP   32
#define SPB  16
#define NBLK (4096 / SPB)

typedef __attribute__((ext_vector_type(8))) short bf16x8;   // 8 bf16 = 4 VGPRs
typedef __attribute__((ext_vector_type(4))) float f32x4;

// packed-weight element offsets (bf16 elements); lo copies at +TOTE
#define OFF_W0   0
#define OFF_W1   16384
#define OFF_W2   81920
#define OFF_W2T  147456
#define OFF_W1T  212992
#define OFF_W0T  278528
#define TOTE     294912

__device__ __forceinline__ float softplus_f(float x) {   // hw exp/log, ~1e-6 abs
    float e = __expf(-fabsf(x));
    return fmaxf(x, 0.0f) + __logf(1.0f + e);
}
__device__ __forceinline__ float sigmoid_f(float x) {
    return 1.0f / (1.0f + __expf(-x));
}
__device__ __forceinline__ unsigned short f2b(float f) {   // RNE float->bf16
    unsigned int u = __float_as_uint(f);
    unsigned int r = (u + 0x7FFFu + ((u >> 16) & 1u)) >> 16;
    return (unsigned short)r;
}
__device__ __forceinline__ float b2f(unsigned short h) {
    return __uint_as_float(((unsigned int)h) << 16);
}

// ---- pack weights (and transposes) into MFMA B-fragment order, split hi/lo ----
__global__ void prep_pack(const float* __restrict__ W0,
                          const float* __restrict__ W1,
                          const float* __restrict__ W2,
                          short* __restrict__ P) {
    int T = blockIdx.x * 256 + threadIdx.x;
    if (T >= 36864) return;
    const float* src; int base, NT, trans, lu, t = T;
    if (t < 2048)               { src = W0; base = OFF_W0;  NT = 16; trans = 0; lu = t; }
    else if ((t -= 2048) < 8192){ src = W1; base = OFF_W1;  NT = 16; trans = 0; lu = t; }
    else if ((t -= 8192) < 8192){ src = W2; base = OFF_W2;  NT = 16; trans = 0; lu = t; }
    else if ((t -= 8192) < 8192){ src = W2; base = OFF_W2T; NT = 16; trans = 1; lu = t; }
    else if ((t -= 8192) < 8192){ src = W1; base = OFF_W1T; NT = 16; trans = 1; lu = t; }
    else              { t -= 8192; src = W0; base = OFF_W0T; NT = 4; trans = 1; lu = t; }
    int frag = lu >> 6, lane = lu & 63;
    int kb = frag / NT, nt = frag - kb * NT;
    int n  = nt * 16 + (lane & 15);
    int k0 = kb * 32 + ((lane >> 4) << 3);
    int N  = NT * 16;
    bf16x8 hv, lv;
    #pragma unroll
    for (int j = 0; j < 8; ++j) {
        int k = k0 + j;
        float w = trans ? src[n * 256 + k] : src[k * N + n];
        unsigned short h = f2b(w);
        unsigned short l = f2b(w - b2f(h));
        hv[j] = (short)h;
        lv[j] = (short)l;
    }
    ((bf16x8*)(P + base))[lu]        = hv;
    ((bf16x8*)(P + TOTE + base))[lu] = lv;
}

// split-bf16 GEMM pass: acc[t] += A(act) x B(packed), 3 MFMAs per fragment.
template<int KB, int NT, int TPW>
__device__ __forceinline__ void gemm_mf(const short* __restrict__ BH,
                                        const short* __restrict__ BL,
                                        const unsigned short (*aH)[264],
                                        const unsigned short (*aL)[264],
                                        int L, int quad, int wv, f32x4* acc)
{
    #pragma unroll
    for (int kb = 0; kb < KB; ++kb) {
        bf16x8 ah = *(const bf16x8*)&aH[L & 15][kb * 32 + quad * 8];
        bf16x8 al = *(const bf16x8*)&aL[L & 15][kb * 32 + quad * 8];
        bf16x8 bh[TPW], bl[TPW];
        #pragma unroll
        for (int t = 0; t < TPW; ++t) {
            int frag = kb * NT + wv * TPW + t;
            bh[t] = ((const bf16x8*)BH)[frag * 64 + L];
            bl[t] = ((const bf16x8*)BL)[frag * 64 + L];
        }
        #pragma unroll
        for (int t = 0; t < TPW; ++t) {
            acc[t] = __builtin_amdgcn_mfma_f32_16x16x32_bf16(ah, bh[t], acc[t], 0, 0, 0);
            acc[t] = __builtin_amdgcn_mfma_f32_16x16x32_bf16(ah, bl[t], acc[t], 0, 0, 0);
            acc[t] = __builtin_amdgcn_mfma_f32_16x16x32_bf16(al, bh[t], acc[t], 0, 0, 0);
        }
    }
}

__global__ __launch_bounds__(256, 2) void chnn_main(
    const float* __restrict__ z, const float* __restrict__ mp,
    const float* __restrict__ B0, const float* __restrict__ B1,
    const float* __restrict__ B2, const float* __restrict__ W3,
    const short* __restrict__ P,
    float* __restrict__ out)
{
    __shared__ __align__(16) unsigned short actH[16][264];
    __shared__ __align__(16) unsigned short actL[16][264];
    __shared__ __align__(16) float rsh[64][SPB];
    __shared__ __align__(16) float vsh[64][SPB];
    __shared__ __align__(16) float gsh[64][SPB];
    __shared__ float invm[NP];
    __shared__ double invmd[NP];
    __shared__ float ge[SPB][NP][2], gd[SPB][NP][2];
    __shared__ double Sdd[SPB][NP], Sed[SPB][NP], Ked[SPB][NP];
    __shared__ double b0d[SPB][NP], b1d[SPB][NP];   // become X1, X0 in place
    __shared__ double wfac[SPB][NP], dinv[SPB][NP];

    const int tid  = threadIdx.x;
    const int L    = tid & 63;
    const int wv   = tid >> 6;
    const int quad = L >> 4;
    const long sbase = (long)blockIdx.x * SPB;

    const short* W0h  = P + OFF_W0;   const short* W0l  = P + TOTE + OFF_W0;
    const short* W1h  = P + OFF_W1;   const short* W1l  = P + TOTE + OFF_W1;
    const short* W2h  = P + OFF_W2;   const short* W2l  = P + TOTE + OFF_W2;
    const short* W2Th = P + OFF_W2T;  const short* W2Tl = P + TOTE + OFF_W2T;
    const short* W1Th = P + OFF_W1T;  const short* W1Tl = P + TOTE + OFF_W1T;
    const short* W0Th = P + OFF_W0T;  const short* W0Tl = P + TOTE + OFF_W0T;

    if (tid < NP) {
        double e = exp(-(double)mp[tid]);
        invmd[tid] = e;
        invm[tid] = (float)e;
    }

    // ---- stage z: 16 samples x 128 ----
    const float* zb = z + sbase * ZD;
    #pragma unroll
    for (int k = 0; k < 8; ++k) {
        int e = k * 256 + tid;          // 0..2047
        int s = e >> 7, idx = e & 127;
        float val = zb[e];
        if (idx < 64) {
            rsh[idx][s] = val;
            unsigned short h = f2b(val);
            actH[s][idx] = h;
            actL[s][idx] = f2b(val - b2f(h));
        } else {
            vsh[idx - 64][s] = val;
        }
    }
    __syncthreads();
    {   // p -> v = inv_m * p  (flat e = j*16+s, particle n = j>>1 = e>>5)
        float* pv = &vsh[0][0];
        #pragma unroll
        for (int k = 0; k < 4; ++k) {
            int e = k * 256 + tid;
            pv[e] *= invm[e >> 5];
        }
    }
    __syncthreads();

    f32x4 acc[4];
    float p0s[4][4], p1s[4][4];
    const int nbase = wv * 64 + (L & 15);

    // ---- L0 ----
    #pragma unroll
    for (int t = 0; t < 4; ++t) {
        float bb = B0[nbase + t * 16];
        acc[t] = (f32x4){bb, bb, bb, bb};
    }
    gemm_mf<2, 16, 4>(W0h, W0l, actH, actL, L, quad, wv, acc);
    #pragma unroll
    for (int t = 0; t < 4; ++t)
        #pragma unroll
        for (int r = 0; r < 4; ++r) p0s[t][r] = acc[t][r];
    __syncthreads();
    #pragma unroll
    for (int t = 0; t < 4; ++t) {
        int n = nbase + t * 16;
        #pragma unroll
        for (int r = 0; r < 4; ++r) {
            int m = quad * 4 + r;
            float h = softplus_f(acc[t][r]);
            unsigned short hh = f2b(h);
            actH[m][n] = hh;
            actL[m][n] = f2b(h - b2f(hh));
        }
    }
    __syncthreads();

    // ---- L1 ----
    #pragma unroll
    for (int t = 0; t < 4; ++t) {
        float bb = B1[nbase + t * 16];
        acc[t] = (f32x4){bb, bb, bb, bb};
    }
    gemm_mf<8, 16, 4>(W1h, W1l, actH, actL, L, quad, wv, acc);
    #pragma unroll
    for (int t = 0; t < 4; ++t)
        #pragma unroll
        for (int r = 0; r < 4; ++r) p1s[t][r] = acc[t][r];
    __syncthreads();
    #pragma unroll
    for (int t = 0; t < 4; ++t) {
        int n = nbase + t * 16;
        #pragma unroll
        for (int r = 0; r < 4; ++r) {
            int m = quad * 4 + r;
            float h = softplus_f(acc[t][r]);
            unsigned short hh = f2b(h);
            actH[m][n] = hh;
            actL[m][n] = f2b(h - b2f(hh));
        }
    }
    __syncthreads();

    // ---- L2 + head: dA = W3[n] * sigmoid(pre2) ----
    #pragma unroll
    for (int t = 0; t < 4; ++t) {
        float bb = B2[nbase + t * 16];
        acc[t] = (f32x4){bb, bb, bb, bb};
    }
    gemm_mf<8, 16, 4>(W2h, W2l, actH, actL, L, quad, wv, acc);
    __syncthreads();
    #pragma unroll
    for (int t = 0; t < 4; ++t) {
        int n = nbase + t * 16;
        float w3 = W3[n];
        #pragma unroll
        for (int r = 0; r < 4; ++r) {
            int m = quad * 4 + r;
            float h = w3 * sigmoid_f(acc[t][r]);
            unsigned short hh = f2b(h);
            actH[m][n] = hh;
            actL[m][n] = f2b(h - b2f(hh));
        }
    }
    __syncthreads();

    // ---- dB = sigmoid(p1) * (dA @ W2^T) ----
    #pragma unroll
    for (int t = 0; t < 4; ++t) acc[t] = (f32x4){0.f, 0.f, 0.f, 0.f};
    gemm_mf<8, 16, 4>(W2Th, W2Tl, actH, actL, L, quad, wv, acc);
    __syncthreads();
    #pragma unroll
    for (int t = 0; t < 4; ++t) {
        int n = nbase + t * 16;
        #pragma unroll
        for (int r = 0; r < 4; ++r) {
            int m = quad * 4 + r;
            float h = acc[t][r] * sigmoid_f(p1s[t][r]);
            unsigned short hh = f2b(h);
            actH[m][n] = hh;
            actL[m][n] = f2b(h - b2f(hh));
        }
    }
    __syncthreads();

    // ---- d0 = sigmoid(p0) * (dB @ W1^T) ----
    #pragma unroll
    for (int t = 0; t < 4; ++t) acc[t] = (f32x4){0.f, 0.f, 0.f, 0.f};
    gemm_mf<8, 16, 4>(W1Th, W1Tl, actH, actL, L, quad, wv, acc);
    __syncthreads();
    #pragma unroll
    for (int t = 0; t < 4; ++t) {
        int n = nbase + t * 16;
        #pragma unroll
        for (int r = 0; r < 4; ++r) {
            int m = quad * 4 + r;
            float h = acc[t][r] * sigmoid_f(p0s[t][r]);
            unsigned short hh = f2b(h);
            actH[m][n] = hh;
            actL[m][n] = f2b(h - b2f(hh));
        }
    }
    __syncthreads();

    // ---- g = d0 @ W0^T  (N=64) ----
    acc[0] = (f32x4){0.f, 0.f, 0.f, 0.f};
    gemm_mf<8, 4, 1>(W0Th, W0Tl, actH, actL, L, quad, wv, acc);
    __syncthreads();
    {
        int i = wv * 16 + (L & 15);
        #pragma unroll
        for (int r = 0; r < 4; ++r) {
            int m = quad * 4 + r;
            gsh[i][m] = acc[0][r];
        }
    }
    __syncthreads();

    // ---- constraint assembly (fp64), 16 samples via u-loop ----
    {
        const int c  = tid & 31;
        const int s0 = tid >> 5;       // 0..7
        double gxa[2], gya[2], gdxa[2], gdya[2];
        #pragma unroll
        for (int u = 0; u < 2; ++u) {
            int s = s0 + 8 * u;
            double gx, gy, gdx, gdy;
            if (c == 0) {
                double r0x = rsh[0][s], r0y = rsh[1][s];
                double v0x = vsh[0][s], v0y = vsh[1][s];
                gx = 2.0 * r0x; gy = 2.0 * r0y; gdx = 2.0 * v0x; gdy = 2.0 * v0y;
                Sdd[s][0] = invmd[0] * (gx * gx + gy * gy);
                b0d[s][0] = gx * v0x + gy * v0y;
                b1d[s][0] = gdx * v0x + gdy * v0y
                          - invmd[0] * (gx * (double)gsh[0][s] + gy * (double)gsh[1][s]);
            } else {
                int aa = 2 * (c - 1), b = 2 * c;
                double dvx = (double)vsh[aa][s] - (double)vsh[b][s];
                double dvy = (double)vsh[aa + 1][s] - (double)vsh[b + 1][s];
                gx = 2.0 * ((double)rsh[aa][s] - (double)rsh[b][s]);
                gy = 2.0 * ((double)rsh[aa + 1][s] - (double)rsh[b + 1][s]);
                gdx = 2.0 * dvx; gdy = 2.0 * dvy;
                Sdd[s][c] = (invmd[c - 1] + invmd[c]) * (gx * gx + gy * gy);
                b0d[s][c] = gx * dvx + gy * dvy;
                double mgx = invmd[c - 1] * (double)gsh[aa][s]     - invmd[c] * (double)gsh[b][s];
                double mgy = invmd[c - 1] * (double)gsh[aa + 1][s] - invmd[c] * (double)gsh[b + 1][s];
                b1d[s][c] = gdx * dvx + gdy * dvy - (gx * mgx + gy * mgy);
            }
            ge[s][c][0] = (float)gx;  ge[s][c][1] = (float)gy;
            gd[s][c][0] = (float)gdx; gd[s][c][1] = (float)gdy;
            gxa[u] = gx; gya[u] = gy; gdxa[u] = gdx; gdya[u] = gdy;
        }
        __syncthreads();
        #pragma unroll
        for (int u = 0; u < 2; ++u) {
            int s = s0 + 8 * u;
            double gx = gxa[u], gy = gya[u], gdx = gdxa[u], gdy = gdya[u];
            if (c < 31) {
                double g1x = ge[s][c + 1][0], g1y = ge[s][c + 1][1];
                double q1x = gd[s][c + 1][0], q1y = gd[s][c + 1][1];
                if (c == 0) {
                    Sed[s][0] = invmd[0] * (gx * g1x + gy * g1y);
                    Ked[s][0] = invmd[0] * ((gdx * g1x + gdy * g1y) - (gx * q1x + gy * q1y));
                } else {
                    Sed[s][c] = -invmd[c] * (gx * g1x + gy * g1y);
                    Ked[s][c] =  invmd[c] * ((gx * q1x + gy * q1y) - (gdx * g1x + gdy * g1y));
                }
            }
        }
    }
    __syncthreads();

    // ---- fp64 Thomas: factor S, solve S X1 = b0 (in place in b0d) ----
    if (tid < SPB) {
        int s = tid;
        double d = Sdd[s][0];
        if (d == 0.0) d = 1e-300;
        dinv[s][0] = 1.0 / d;
        double y = b0d[s][0];
        for (int c = 1; c < NP; ++c) {
            double e = Sed[s][c - 1];
            double w = e * dinv[s][c - 1];
            wfac[s][c - 1] = w;
            d = Sdd[s][c] - w * e;
            if (d == 0.0) d = 1e-300;
            dinv[s][c] = 1.0 / d;
            y = b0d[s][c] - w * y;
            b0d[s][c] = y;
        }
        double x = b0d[s][31] * dinv[s][31];
        b0d[s][31] = x;
        for (int c = 30; c >= 0; --c) {
            x = (b0d[s][c] - Sed[s][c] * x) * dinv[s][c];
            b0d[s][c] = x;
        }
    }
    __syncthreads();

    // ---- rhs2 = K X1 - b1 (in place in b1d) ----
    {
        int c = tid & 31, s0 = tid >> 5;
        #pragma unroll
        for (int u = 0; u < 2; ++u) {
            int s = s0 + 8 * u;
            double kx = 0.0;
            if (c < 31) kx += Ked[s][c] * b0d[s][c + 1];
            if (c > 0)  kx -= Ked[s][c - 1] * b0d[s][c - 1];
            b1d[s][c] = kx - b1d[s][c];
        }
    }
    __syncthreads();

    // ---- solve S X0 = rhs2 with stored factors (in place in b1d) ----
    if (tid < SPB) {
        int s = tid;
        double y = b1d[s][0];
        for (int c = 1; c < NP; ++c) {
            y = b1d[s][c] - wfac[s][c - 1] * y;
            b1d[s][c] = y;
        }
        double x = b1d[s][31] * dinv[s][31];
        b1d[s][31] = x;
        for (int c = 30; c >= 0; --c) {
            x = (b1d[s][c] - Sed[s][c] * x) * dinv[s][c];
            b1d[s][c] = x;
        }
    }
    __syncthreads();

    // ---- output: [v - M^-1 G X1 ; -g + G X0 + Gdot X1]   (X1=b0d, X0=b1d) ----
    float* ob = out + sbase * ZD;
    #pragma unroll
    for (int k = 0; k < 8; ++k) {
        int e = k * 256 + tid;
        int s = e >> 7, idx = e & 127;
        int j = idx & 63;
        int n = j >> 1, d = j & 1;
        float res;
        if (idx < 64) {
            double Gx1 = (n == 0) ? (double)ge[s][0][d] * b0d[s][0]
                                  : -(double)ge[s][n][d] * b0d[s][n];
            if (n < 31) Gx1 += (double)ge[s][n + 1][d] * b0d[s][n + 1];
            res = (float)((double)vsh[j][s] - invmd[n] * Gx1);
        } else {
            double Gx0 = (n == 0) ? (double)ge[s][0][d] * b1d[s][0]
                                  : -(double)ge[s][n][d] * b1d[s][n];
            if (n < 31) Gx0 += (double)ge[s][n + 1][d] * b1d[s][n + 1];
            double Gd1 = (n == 0) ? (double)gd[s][0][d] * b0d[s][0]
                                  : -(double)gd[s][n][d] * b0d[s][n];
            if (n < 31) Gd1 += (double)gd[s][n + 1][d] * b0d[s][n + 1];
            res = (float)(-(double)gsh[j][s] + Gx0 + Gd1);
        }
        ob[e] = res;
    }
}

extern "C" void kernel_launch(void* const* d_in, const int* in_sizes, int n_in,
                              void* d_out, int out_size, void* d_ws, size_t ws_size,
                              hipStream_t stream) {
    const float* z  = (const float*)d_in[1];
    const float* mp = (const float*)d_in[2];
    const float* W0 = (const float*)d_in[3];
    const float* B0 = (const float*)d_in[4];
    const float* W1 = (const float*)d_in[5];
    const float* B1 = (const float*)d_in[6];
    const float* W2 = (const float*)d_in[7];
    const float* B2 = (const float*)d_in[8];
    const float* W3 = (const float*)d_in[9];

    short* P = (short*)d_ws;   // 2*TOTE bf16 elements = 1.15 MB packed weights

    prep_pack<<<144, 256, 0, stream>>>(W0, W1, W2, P);
    chnn_main<<<NBLK, 256, 0, stream>>>(z, mp, B0, B1, B2, W3, P, (float*)d_out);
}

// Round 10
// 114.931 us; speedup vs baseline: 1.2100x; 1.2100x over previous
//
#include <hip/hip_runtime.h>

#define ZD   128
#define NP   32
#define SPB  16
#define NBLK (4096 / SPB)
#define NTH  512

typedef __attribute__((ext_vector_type(8))) short bf16x8;   // 8 bf16 = 4 VGPRs
typedef __attribute__((ext_vector_type(4))) float f32x4;

// packed-weight element offsets (bf16 elements); lo copies at +TOTE
#define OFF_W0   0
#define OFF_W1   16384
#define OFF_W2   81920
#define OFF_W2T  147456
#define OFF_W1T  212992
#define OFF_W0T  278528
#define TOTE     294912

__device__ __forceinline__ float softplus_f(float x) {   // hw exp/log, ~1e-6 abs
    float e = __expf(-fabsf(x));
    return fmaxf(x, 0.0f) + __logf(1.0f + e);
}
__device__ __forceinline__ float sigmoid_f(float x) {
    return 1.0f / (1.0f + __expf(-x));
}
__device__ __forceinline__ unsigned short f2b(float f) {   // RNE float->bf16
    unsigned int u = __float_as_uint(f);
    unsigned int r = (u + 0x7FFFu + ((u >> 16) & 1u)) >> 16;
    return (unsigned short)r;
}
__device__ __forceinline__ float b2f(unsigned short h) {
    return __uint_as_float(((unsigned int)h) << 16);
}

// ---- pack weights (and transposes) into MFMA B-fragment order, split hi/lo ----
__global__ void prep_pack(const float* __restrict__ W0,
                          const float* __restrict__ W1,
                          const float* __restrict__ W2,
                          short* __restrict__ P) {
    int T = blockIdx.x * 256 + threadIdx.x;
    if (T >= 36864) return;
    const float* src; int base, NT, trans, lu, t = T;
    if (t < 2048)               { src = W0; base = OFF_W0;  NT = 16; trans = 0; lu = t; }
    else if ((t -= 2048) < 8192){ src = W1; base = OFF_W1;  NT = 16; trans = 0; lu = t; }
    else if ((t -= 8192) < 8192){ src = W2; base = OFF_W2;  NT = 16; trans = 0; lu = t; }
    else if ((t -= 8192) < 8192){ src = W2; base = OFF_W2T; NT = 16; trans = 1; lu = t; }
    else if ((t -= 8192) < 8192){ src = W1; base = OFF_W1T; NT = 16; trans = 1; lu = t; }
    else              { t -= 8192; src = W0; base = OFF_W0T; NT = 4; trans = 1; lu = t; }
    int frag = lu >> 6, lane = lu & 63;
    int kb = frag / NT, nt = frag - kb * NT;
    int n  = nt * 16 + (lane & 15);
    int k0 = kb * 32 + ((lane >> 4) << 3);
    int N  = NT * 16;
    bf16x8 hv, lv;
    #pragma unroll
    for (int j = 0; j < 8; ++j) {
        int k = k0 + j;
        float w = trans ? src[n * 256 + k] : src[k * N + n];
        unsigned short h = f2b(w);
        unsigned short l = f2b(w - b2f(h));
        hv[j] = (short)h;
        lv[j] = (short)l;
    }
    ((bf16x8*)(P + base))[lu]        = hv;
    ((bf16x8*)(P + TOTE + base))[lu] = lv;
}

// split-bf16 GEMM pass: acc[t] += A(act) x B(packed), 3 MFMAs per fragment.
// Wave wvx covers tiles [wvx*TPW, wvx*TPW+TPW) of NT total.
template<int KB, int NT, int TPW>
__device__ __forceinline__ void gemm_mf(const short* __restrict__ BH,
                                        const short* __restrict__ BL,
                                        const unsigned short (*aH)[264],
                                        const unsigned short (*aL)[264],
                                        int L, int quad, int wvx, f32x4* acc)
{
    #pragma unroll
    for (int kb = 0; kb < KB; ++kb) {
        bf16x8 ah = *(const bf16x8*)&aH[L & 15][kb * 32 + quad * 8];
        bf16x8 al = *(const bf16x8*)&aL[L & 15][kb * 32 + quad * 8];
        bf16x8 bh[TPW], bl[TPW];
        #pragma unroll
        for (int t = 0; t < TPW; ++t) {
            int frag = kb * NT + wvx * TPW + t;
            bh[t] = ((const bf16x8*)BH)[frag * 64 + L];
            bl[t] = ((const bf16x8*)BL)[frag * 64 + L];
        }
        #pragma unroll
        for (int t = 0; t < TPW; ++t) {
            acc[t] = __builtin_amdgcn_mfma_f32_16x16x32_bf16(ah, bh[t], acc[t], 0, 0, 0);
            acc[t] = __builtin_amdgcn_mfma_f32_16x16x32_bf16(ah, bl[t], acc[t], 0, 0, 0);
            acc[t] = __builtin_amdgcn_mfma_f32_16x16x32_bf16(al, bh[t], acc[t], 0, 0, 0);
        }
    }
}

__global__ __launch_bounds__(NTH, 2) void chnn_main(
    const float* __restrict__ z, const float* __restrict__ mp,
    const float* __restrict__ B0, const float* __restrict__ B1,
    const float* __restrict__ B2, const float* __restrict__ W3,
    const short* __restrict__ P,
    float* __restrict__ out)
{
    // ping-pong activation buffers: pass i reads buf p, writes buf p^1
    __shared__ __align__(16) unsigned short actH[2][16][264];
    __shared__ __align__(16) unsigned short actL[2][16][264];
    __shared__ __align__(16) float rsh[64][SPB];
    __shared__ __align__(16) float vsh[64][SPB];
    __shared__ __align__(16) float gsh[64][SPB];
    __shared__ float invm[NP];
    __shared__ double invmd[NP];
    __shared__ float ge[SPB][NP][2], gd[SPB][NP][2];
    __shared__ double Sdd[SPB][NP], Sed[SPB][NP], Ked[SPB][NP];
    __shared__ double b0d[SPB][NP], b1d[SPB][NP];   // become X1, X0 in place
    __shared__ double wfac[SPB][NP], dinv[SPB][NP];

    const int tid  = threadIdx.x;
    const int L    = tid & 63;
    const int wv   = tid >> 6;       // 0..7
    const int quad = L >> 4;
    const long sbase = (long)blockIdx.x * SPB;

    const short* W0h  = P + OFF_W0;   const short* W0l  = P + TOTE + OFF_W0;
    const short* W1h  = P + OFF_W1;   const short* W1l  = P + TOTE + OFF_W1;
    const short* W2h  = P + OFF_W2;   const short* W2l  = P + TOTE + OFF_W2;
    const short* W2Th = P + OFF_W2T;  const short* W2Tl = P + TOTE + OFF_W2T;
    const short* W1Th = P + OFF_W1T;  const short* W1Tl = P + TOTE + OFF_W1T;
    const short* W0Th = P + OFF_W0T;  const short* W0Tl = P + TOTE + OFF_W0T;

    if (tid < NP) {
        double e = exp(-(double)mp[tid]);
        invmd[tid] = e;
        invm[tid] = (float)e;
    }

    // ---- stage z: 16 samples x 128; r split-bf16 into buf 0 ----
    const float* zb = z + sbase * ZD;
    #pragma unroll
    for (int k = 0; k < 4; ++k) {
        int e = k * NTH + tid;          // 0..2047
        int s = e >> 7, idx = e & 127;
        float val = zb[e];
        if (idx < 64) {
            rsh[idx][s] = val;
            unsigned short h = f2b(val);
            actH[0][s][idx] = h;
            actL[0][s][idx] = f2b(val - b2f(h));
        } else {
            vsh[idx - 64][s] = val;
        }
    }
    __syncthreads();
    {   // p -> v = inv_m * p  (flat e = j*16+s, particle n = e>>5)
        float* pv = &vsh[0][0];
        #pragma unroll
        for (int k = 0; k < 2; ++k) {
            int e = k * NTH + tid;
            pv[e] *= invm[e >> 5];
        }
    }
    __syncthreads();

    f32x4 acc[2];
    float p0s[2][4], p1s[2][4];
    const int nbase = wv * 32 + (L & 15);    // 2 tiles/wave, 32 units apart

    // ---- L0: reads buf0, writes buf1 ----
    #pragma unroll
    for (int t = 0; t < 2; ++t) {
        float bb = B0[nbase + t * 16];
        acc[t] = (f32x4){bb, bb, bb, bb};
    }
    gemm_mf<2, 16, 2>(W0h, W0l, actH[0], actL[0], L, quad, wv, acc);
    #pragma unroll
    for (int t = 0; t < 2; ++t) {
        int n = nbase + t * 16;
        #pragma unroll
        for (int r = 0; r < 4; ++r) {
            p0s[t][r] = acc[t][r];
            int m = quad * 4 + r;
            float h = softplus_f(acc[t][r]);
            unsigned short hh = f2b(h);
            actH[1][m][n] = hh;
            actL[1][m][n] = f2b(h - b2f(hh));
        }
    }
    __syncthreads();

    // ---- L1: reads buf1, writes buf0 ----
    #pragma unroll
    for (int t = 0; t < 2; ++t) {
        float bb = B1[nbase + t * 16];
        acc[t] = (f32x4){bb, bb, bb, bb};
    }
    gemm_mf<8, 16, 2>(W1h, W1l, actH[1], actL[1], L, quad, wv, acc);
    #pragma unroll
    for (int t = 0; t < 2; ++t) {
        int n = nbase + t * 16;
        #pragma unroll
        for (int r = 0; r < 4; ++r) {
            p1s[t][r] = acc[t][r];
            int m = quad * 4 + r;
            float h = softplus_f(acc[t][r]);
            unsigned short hh = f2b(h);
            actH[0][m][n] = hh;
            actL[0][m][n] = f2b(h - b2f(hh));
        }
    }
    __syncthreads();

    // ---- L2 + head: dA = W3[n]*sigmoid(pre2); reads buf0, writes buf1 ----
    #pragma unroll
    for (int t = 0; t < 2; ++t) {
        float bb = B2[nbase + t * 16];
        acc[t] = (f32x4){bb, bb, bb, bb};
    }
    gemm_mf<8, 16, 2>(W2h, W2l, actH[0], actL[0], L, quad, wv, acc);
    #pragma unroll
    for (int t = 0; t < 2; ++t) {
        int n = nbase + t * 16;
        float w3 = W3[n];
        #pragma unroll
        for (int r = 0; r < 4; ++r) {
            int m = quad * 4 + r;
            float h = w3 * sigmoid_f(acc[t][r]);
            unsigned short hh = f2b(h);
            actH[1][m][n] = hh;
            actL[1][m][n] = f2b(h - b2f(hh));
        }
    }
    __syncthreads();

    // ---- dB = sigmoid(p1)*(dA @ W2^T): reads buf1, writes buf0 ----
    #pragma unroll
    for (int t = 0; t < 2; ++t) acc[t] = (f32x4){0.f, 0.f, 0.f, 0.f};
    gemm_mf<8, 16, 2>(W2Th, W2Tl, actH[1], actL[1], L, quad, wv, acc);
    #pragma unroll
    for (int t = 0; t < 2; ++t) {
        int n = nbase + t * 16;
        #pragma unroll
        for (int r = 0; r < 4; ++r) {
            int m = quad * 4 + r;
            float h = acc[t][r] * sigmoid_f(p1s[t][r]);
            unsigned short hh = f2b(h);
            actH[0][m][n] = hh;
            actL[0][m][n] = f2b(h - b2f(hh));
        }
    }
    __syncthreads();

    // ---- d0 = sigmoid(p0)*(dB @ W1^T): reads buf0, writes buf1 ----
    #pragma unroll
    for (int t = 0; t < 2; ++t) acc[t] = (f32x4){0.f, 0.f, 0.f, 0.f};
    gemm_mf<8, 16, 2>(W1Th, W1Tl, actH[0], actL[0], L, quad, wv, acc);
    #pragma unroll
    for (int t = 0; t < 2; ++t) {
        int n = nbase + t * 16;
        #pragma unroll
        for (int r = 0; r < 4; ++r) {
            int m = quad * 4 + r;
            float h = acc[t][r] * sigmoid_f(p0s[t][r]);
            unsigned short hh = f2b(h);
            actH[1][m][n] = hh;
            actL[1][m][n] = f2b(h - b2f(hh));
        }
    }
    __syncthreads();

    // ---- g = d0 @ W0^T (N=64): waves 0..3 only, reads buf1 ----
    if (wv < 4) {
        acc[0] = (f32x4){0.f, 0.f, 0.f, 0.f};
        gemm_mf<8, 4, 1>(W0Th, W0Tl, actH[1], actL[1], L, quad, wv, acc);
        int i = wv * 16 + (L & 15);
        #pragma unroll
        for (int r = 0; r < 4; ++r) {
            int m = quad * 4 + r;
            gsh[i][m] = acc[0][r];
        }
    }
    __syncthreads();

    // ---- constraint assembly (fp64): 512 thr = 16 samples x 32 constraints ----
    {
        const int c = tid & 31;
        const int s = tid >> 5;          // 0..15
        double gx, gy, gdx, gdy;
        if (c == 0) {
            double r0x = rsh[0][s], r0y = rsh[1][s];
            double v0x = vsh[0][s], v0y = vsh[1][s];
            gx = 2.0 * r0x; gy = 2.0 * r0y; gdx = 2.0 * v0x; gdy = 2.0 * v0y;
            Sdd[s][0] = invmd[0] * (gx * gx + gy * gy);
            b0d[s][0] = gx * v0x + gy * v0y;
            b1d[s][0] = gdx * v0x + gdy * v0y
                      - invmd[0] * (gx * (double)gsh[0][s] + gy * (double)gsh[1][s]);
        } else {
            int aa = 2 * (c - 1), b = 2 * c;
            double dvx = (double)vsh[aa][s] - (double)vsh[b][s];
            double dvy = (double)vsh[aa + 1][s] - (double)vsh[b + 1][s];
            gx = 2.0 * ((double)rsh[aa][s] - (double)rsh[b][s]);
            gy = 2.0 * ((double)rsh[aa + 1][s] - (double)rsh[b + 1][s]);
            gdx = 2.0 * dvx; gdy = 2.0 * dvy;
            Sdd[s][c] = (invmd[c - 1] + invmd[c]) * (gx * gx + gy * gy);
            b0d[s][c] = gx * dvx + gy * dvy;
            double mgx = invmd[c - 1] * (double)gsh[aa][s]     - invmd[c] * (double)gsh[b][s];
            double mgy = invmd[c - 1] * (double)gsh[aa + 1][s] - invmd[c] * (double)gsh[b + 1][s];
            b1d[s][c] = gdx * dvx + gdy * dvy - (gx * mgx + gy * mgy);
        }
        ge[s][c][0] = (float)gx;  ge[s][c][1] = (float)gy;
        gd[s][c][0] = (float)gdx; gd[s][c][1] = (float)gdy;
        __syncthreads();
        if (c < 31) {
            double g1x = ge[s][c + 1][0], g1y = ge[s][c + 1][1];
            double q1x = gd[s][c + 1][0], q1y = gd[s][c + 1][1];
            if (c == 0) {
                Sed[s][0] = invmd[0] * (gx * g1x + gy * g1y);
                Ked[s][0] = invmd[0] * ((gdx * g1x + gdy * g1y) - (gx * q1x + gy * q1y));
            } else {
                Sed[s][c] = -invmd[c] * (gx * g1x + gy * g1y);
                Ked[s][c] =  invmd[c] * ((gx * q1x + gy * q1y) - (gdx * g1x + gdy * g1y));
            }
        }
    }
    __syncthreads();

    // ---- fp64 Thomas: factor S, solve S X1 = b0 (in place in b0d) ----
    if (tid < SPB) {
        int s = tid;
        double d = Sdd[s][0];
        if (d == 0.0) d = 1e-300;
        dinv[s][0] = 1.0 / d;
        double y = b0d[s][0];
        for (int c = 1; c < NP; ++c) {
            double e = Sed[s][c - 1];
            double w = e * dinv[s][c - 1];
            wfac[s][c - 1] = w;
            d = Sdd[s][c] - w * e;
            if (d == 0.0) d = 1e-300;
            dinv[s][c] = 1.0 / d;
            y = b0d[s][c] - w * y;
            b0d[s][c] = y;
        }
        double x = b0d[s][31] * dinv[s][31];
        b0d[s][31] = x;
        for (int c = 30; c >= 0; --c) {
            x = (b0d[s][c] - Sed[s][c] * x) * dinv[s][c];
            b0d[s][c] = x;
        }
    }
    __syncthreads();

    // ---- rhs2 = K X1 - b1 (in place in b1d) ----
    {
        int c = tid & 31, s = tid >> 5;
        double kx = 0.0;
        if (c < 31) kx += Ked[s][c] * b0d[s][c + 1];
        if (c > 0)  kx -= Ked[s][c - 1] * b0d[s][c - 1];
        b1d[s][c] = kx - b1d[s][c];
    }
    __syncthreads();

    // ---- solve S X0 = rhs2 with stored factors (in place in b1d) ----
    if (tid < SPB) {
        int s = tid;
        double y = b1d[s][0];
        for (int c = 1; c < NP; ++c) {
            y = b1d[s][c] - wfac[s][c - 1] * y;
            b1d[s][c] = y;
        }
        double x = b1d[s][31] * dinv[s][31];
        b1d[s][31] = x;
        for (int c = 30; c >= 0; --c) {
            x = (b1d[s][c] - Sed[s][c] * x) * dinv[s][c];
            b1d[s][c] = x;
        }
    }
    __syncthreads();

    // ---- output: [v - M^-1 G X1 ; -g + G X0 + Gdot X1]   (X1=b0d, X0=b1d) ----
    float* ob = out + sbase * ZD;
    #pragma unroll
    for (int k = 0; k < 4; ++k) {
        int e = k * NTH + tid;
        int s = e >> 7, idx = e & 127;
        int j = idx & 63;
        int n = j >> 1, d = j & 1;
        float res;
        if (idx < 64) {
            double Gx1 = (n == 0) ? (double)ge[s][0][d] * b0d[s][0]
                                  : -(double)ge[s][n][d] * b0d[s][n];
            if (n < 31) Gx1 += (double)ge[s][n + 1][d] * b0d[s][n + 1];
            res = (float)((double)vsh[j][s] - invmd[n] * Gx1);
        } else {
            double Gx0 = (n == 0) ? (double)ge[s][0][d] * b1d[s][0]
                                  : -(double)ge[s][n][d] * b1d[s][n];
            if (n < 31) Gx0 += (double)ge[s][n + 1][d] * b1d[s][n + 1];
            double Gd1 = (n == 0) ? (double)gd[s][0][d] * b0d[s][0]
                                  : -(double)gd[s][n][d] * b0d[s][n];
            if (n < 31) Gd1 += (double)gd[s][n + 1][d] * b0d[s][n + 1];
            res = (float)(-(double)gsh[j][s] + Gx0 + Gd1);
        }
        ob[e] = res;
    }
}

extern "C" void kernel_launch(void* const* d_in, const int* in_sizes, int n_in,
                              void* d_out, int out_size, void* d_ws, size_t ws_size,
                              hipStream_t stream) {
    const float* z  = (const float*)d_in[1];
    const float* mp = (const float*)d_in[2];
    const float* W0 = (const float*)d_in[3];
    const float* B0 = (const float*)d_in[4];
    const float* W1 = (const float*)d_in[5];
    const float* B1 = (const float*)d_in[6];
    const float* W2 = (const float*)d_in[7];
    const float* B2 = (const float*)d_in[8];
    const float* W3 = (const float*)d_in[9];

    short* P = (short*)d_ws;   // 2*TOTE bf16 elements = 1.15 MB packed weights

    prep_pack<<<144, 256, 0, stream>>>(W0, W1, W2, P);
    chnn_main<<<NBLK, NTH, 0, stream>>>(z, mp, B0, B1, B2, W3, P, (float*)d_out);
}

// Round 11
// 94.491 us; speedup vs baseline: 1.4717x; 1.2163x over previous
//
#include <hip/hip_runtime.h>

#define ZD   128
#define NP   32
#define SPB  16
#define NBLK (4096 / SPB)
#define NTH  512

typedef __attribute__((ext_vector_type(8))) short bf16x8;   // 8 bf16 = 4 VGPRs
typedef __attribute__((ext_vector_type(4))) float f32x4;

// packed-weight element offsets (bf16 elements), hi only
#define OFF_W0   0
#define OFF_W1   16384
#define OFF_W2   81920
#define OFF_W2T  147456
#define OFF_W1T  212992
#define OFF_W0T  278528

__device__ __forceinline__ float softplus_f(float x) {   // hw exp/log, ~1e-6 abs
    float e = __expf(-fabsf(x));
    return fmaxf(x, 0.0f) + __logf(1.0f + e);
}
__device__ __forceinline__ float sigmoid_f(float x) {
    return 1.0f / (1.0f + __expf(-x));
}
__device__ __forceinline__ unsigned short f2b(float f) {   // RNE float->bf16
    unsigned int u = __float_as_uint(f);
    unsigned int r = (u + 0x7FFFu + ((u >> 16) & 1u)) >> 16;
    return (unsigned short)r;
}

// ---- pack weights (and transposes) into MFMA B-fragment order (bf16 hi) ----
__global__ void prep_pack(const float* __restrict__ W0,
                          const float* __restrict__ W1,
                          const float* __restrict__ W2,
                          short* __restrict__ P) {
    int T = blockIdx.x * 256 + threadIdx.x;
    if (T >= 36864) return;
    const float* src; int base, NT, trans, lu, t = T;
    if (t < 2048)               { src = W0; base = OFF_W0;  NT = 16; trans = 0; lu = t; }
    else if ((t -= 2048) < 8192){ src = W1; base = OFF_W1;  NT = 16; trans = 0; lu = t; }
    else if ((t -= 8192) < 8192){ src = W2; base = OFF_W2;  NT = 16; trans = 0; lu = t; }
    else if ((t -= 8192) < 8192){ src = W2; base = OFF_W2T; NT = 16; trans = 1; lu = t; }
    else if ((t -= 8192) < 8192){ src = W1; base = OFF_W1T; NT = 16; trans = 1; lu = t; }
    else              { t -= 8192; src = W0; base = OFF_W0T; NT = 4; trans = 1; lu = t; }
    int frag = lu >> 6, lane = lu & 63;
    int kb = frag / NT, nt = frag - kb * NT;
    int n  = nt * 16 + (lane & 15);
    int k0 = kb * 32 + ((lane >> 4) << 3);
    int N  = NT * 16;
    bf16x8 hv;
    #pragma unroll
    for (int j = 0; j < 8; ++j) {
        int k = k0 + j;
        float w = trans ? src[n * 256 + k] : src[k * N + n];
        hv[j] = (short)f2b(w);
    }
    ((bf16x8*)(P + base))[lu] = hv;
}

// load B fragments for a pass into registers (global, barrier-independent)
template<int KB, int NT, int TPW>
__device__ __forceinline__ void load_B(const short* __restrict__ BH,
                                       int L, int wvx, bf16x8* dst) {
    #pragma unroll
    for (int kb = 0; kb < KB; ++kb)
        #pragma unroll
        for (int t = 0; t < TPW; ++t)
            dst[kb * TPW + t] = ((const bf16x8*)BH)[(kb * NT + wvx * TPW + t) * 64 + L];
}

// MFMAs for a pass using pre-loaded B registers
template<int KB, int TPW>
__device__ __forceinline__ void mfma_B(const unsigned short (*aH)[264],
                                       int L, int quad,
                                       const bf16x8* fr, f32x4* acc) {
    #pragma unroll
    for (int kb = 0; kb < KB; ++kb) {
        bf16x8 ah = *(const bf16x8*)&aH[L & 15][kb * 32 + quad * 8];
        #pragma unroll
        for (int t = 0; t < TPW; ++t)
            acc[t] = __builtin_amdgcn_mfma_f32_16x16x32_bf16(ah, fr[kb * TPW + t],
                                                             acc[t], 0, 0, 0);
    }
}

__global__ __launch_bounds__(NTH, 2) void chnn_main(
    const float* __restrict__ z, const float* __restrict__ mp,
    const float* __restrict__ B0, const float* __restrict__ B1,
    const float* __restrict__ B2, const float* __restrict__ W3,
    const short* __restrict__ P,
    float* __restrict__ out)
{
    // ping-pong activation buffers: pass i reads buf p, writes buf p^1
    __shared__ __align__(16) unsigned short actH[2][16][264];
    __shared__ __align__(16) float rsh[64][SPB];
    __shared__ __align__(16) float vsh[64][SPB];
    __shared__ __align__(16) float gsh[64][SPB];
    __shared__ float invm[NP];
    __shared__ double invmd[NP];
    __shared__ float ge[SPB][NP][2], gd[SPB][NP][2];
    __shared__ double Sdd[SPB][NP], Sed[SPB][NP], Ked[SPB][NP];
    __shared__ double b0d[SPB][NP], b1d[SPB][NP];   // become X1, X0 in place
    __shared__ double wfac[SPB][NP], dinv[SPB][NP];

    const int tid  = threadIdx.x;
    const int L    = tid & 63;
    const int wv   = tid >> 6;       // 0..7
    const int quad = L >> 4;
    const long sbase = (long)blockIdx.x * SPB;

    if (tid < NP) {
        double e = exp(-(double)mp[tid]);
        invmd[tid] = e;
        invm[tid] = (float)e;
    }

    bf16x8 frA[16], frB[16];
    // prefetch L0 weights immediately (independent of staging)
    load_B<2, 16, 2>(P + OFF_W0, L, wv, frA);

    // ---- stage z: 16 samples x 128; r bf16 into buf 0 ----
    const float* zb = z + sbase * ZD;
    #pragma unroll
    for (int k = 0; k < 4; ++k) {
        int e = k * NTH + tid;          // 0..2047
        int s = e >> 7, idx = e & 127;
        float val = zb[e];
        if (idx < 64) {
            rsh[idx][s] = val;
            actH[0][s][idx] = f2b(val);
        } else {
            vsh[idx - 64][s] = val;
        }
    }
    __syncthreads();
    {   // p -> v = inv_m * p  (flat e = j*16+s, particle n = e>>5)
        float* pv = &vsh[0][0];
        #pragma unroll
        for (int k = 0; k < 2; ++k) {
            int e = k * NTH + tid;
            pv[e] *= invm[e >> 5];
        }
    }
    __syncthreads();

    f32x4 acc[2];
    float p0s[2][4], p1s[2][4];
    const int nbase = wv * 32 + (L & 15);    // 2 tiles/wave, 32 units apart

    // ---- L0: reads buf0 (frA), writes buf1; prefetch W1 -> frB ----
    load_B<8, 16, 2>(P + OFF_W1, L, wv, frB);
    #pragma unroll
    for (int t = 0; t < 2; ++t) {
        float bb = B0[nbase + t * 16];
        acc[t] = (f32x4){bb, bb, bb, bb};
    }
    mfma_B<2, 2>(actH[0], L, quad, frA, acc);
    #pragma unroll
    for (int t = 0; t < 2; ++t) {
        int n = nbase + t * 16;
        #pragma unroll
        for (int r = 0; r < 4; ++r) {
            p0s[t][r] = acc[t][r];
            actH[1][quad * 4 + r][n] = f2b(softplus_f(acc[t][r]));
        }
    }
    __syncthreads();

    // ---- L1: reads buf1 (frB), writes buf0; prefetch W2 -> frA ----
    load_B<8, 16, 2>(P + OFF_W2, L, wv, frA);
    #pragma unroll
    for (int t = 0; t < 2; ++t) {
        float bb = B1[nbase + t * 16];
        acc[t] = (f32x4){bb, bb, bb, bb};
    }
    mfma_B<8, 2>(actH[1], L, quad, frB, acc);
    #pragma unroll
    for (int t = 0; t < 2; ++t) {
        int n = nbase + t * 16;
        #pragma unroll
        for (int r = 0; r < 4; ++r) {
            p1s[t][r] = acc[t][r];
            actH[0][quad * 4 + r][n] = f2b(softplus_f(acc[t][r]));
        }
    }
    __syncthreads();

    // ---- L2 + head: reads buf0 (frA), writes buf1; prefetch W2T -> frB ----
    load_B<8, 16, 2>(P + OFF_W2T, L, wv, frB);
    #pragma unroll
    for (int t = 0; t < 2; ++t) {
        float bb = B2[nbase + t * 16];
        acc[t] = (f32x4){bb, bb, bb, bb};
    }
    mfma_B<8, 2>(actH[0], L, quad, frA, acc);
    #pragma unroll
    for (int t = 0; t < 2; ++t) {
        int n = nbase + t * 16;
        float w3 = W3[n];
        #pragma unroll
        for (int r = 0; r < 4; ++r)
            actH[1][quad * 4 + r][n] = f2b(w3 * sigmoid_f(acc[t][r]));
    }
    __syncthreads();

    // ---- dB = sigmoid(p1)*(dA @ W2^T): reads buf1 (frB), writes buf0 ----
    load_B<8, 16, 2>(P + OFF_W1T, L, wv, frA);
    #pragma unroll
    for (int t = 0; t < 2; ++t) acc[t] = (f32x4){0.f, 0.f, 0.f, 0.f};
    mfma_B<8, 2>(actH[1], L, quad, frB, acc);
    #pragma unroll
    for (int t = 0; t < 2; ++t) {
        int n = nbase + t * 16;
        #pragma unroll
        for (int r = 0; r < 4; ++r)
            actH[0][quad * 4 + r][n] = f2b(acc[t][r] * sigmoid_f(p1s[t][r]));
    }
    __syncthreads();

    // ---- d0 = sigmoid(p0)*(dB @ W1^T): reads buf0 (frA), writes buf1 ----
    if (wv < 4) load_B<8, 4, 1>(P + OFF_W0T, L, wv, frB);
    #pragma unroll
    for (int t = 0; t < 2; ++t) acc[t] = (f32x4){0.f, 0.f, 0.f, 0.f};
    mfma_B<8, 2>(actH[0], L, quad, frA, acc);
    #pragma unroll
    for (int t = 0; t < 2; ++t) {
        int n = nbase + t * 16;
        #pragma unroll
        for (int r = 0; r < 4; ++r)
            actH[1][quad * 4 + r][n] = f2b(acc[t][r] * sigmoid_f(p0s[t][r]));
    }
    __syncthreads();

    // ---- g = d0 @ W0^T (N=64): waves 0..3, reads buf1 (frB) ----
    if (wv < 4) {
        acc[0] = (f32x4){0.f, 0.f, 0.f, 0.f};
        mfma_B<8, 1>(actH[1], L, quad, frB, acc);
        int i = wv * 16 + (L & 15);
        #pragma unroll
        for (int r = 0; r < 4; ++r)
            gsh[i][quad * 4 + r] = acc[0][r];
    }
    __syncthreads();

    // ---- constraint assembly (fp64): 512 thr = 16 samples x 32 constraints ----
    {
        const int c = tid & 31;
        const int s = tid >> 5;          // 0..15
        double gx, gy, gdx, gdy;
        if (c == 0) {
            double r0x = rsh[0][s], r0y = rsh[1][s];
            double v0x = vsh[0][s], v0y = vsh[1][s];
            gx = 2.0 * r0x; gy = 2.0 * r0y; gdx = 2.0 * v0x; gdy = 2.0 * v0y;
            Sdd[s][0] = invmd[0] * (gx * gx + gy * gy);
            b0d[s][0] = gx * v0x + gy * v0y;
            b1d[s][0] = gdx * v0x + gdy * v0y
                      - invmd[0] * (gx * (double)gsh[0][s] + gy * (double)gsh[1][s]);
        } else {
            int aa = 2 * (c - 1), b = 2 * c;
            double dvx = (double)vsh[aa][s] - (double)vsh[b][s];
            double dvy = (double)vsh[aa + 1][s] - (double)vsh[b + 1][s];
            gx = 2.0 * ((double)rsh[aa][s] - (double)rsh[b][s]);
            gy = 2.0 * ((double)rsh[aa + 1][s] - (double)rsh[b + 1][s]);
            gdx = 2.0 * dvx; gdy = 2.0 * dvy;
            Sdd[s][c] = (invmd[c - 1] + invmd[c]) * (gx * gx + gy * gy);
            b0d[s][c] = gx * dvx + gy * dvy;
            double mgx = invmd[c - 1] * (double)gsh[aa][s]     - invmd[c] * (double)gsh[b][s];
            double mgy = invmd[c - 1] * (double)gsh[aa + 1][s] - invmd[c] * (double)gsh[b + 1][s];
            b1d[s][c] = gdx * dvx + gdy * dvy - (gx * mgx + gy * mgy);
        }
        ge[s][c][0] = (float)gx;  ge[s][c][1] = (float)gy;
        gd[s][c][0] = (float)gdx; gd[s][c][1] = (float)gdy;
        __syncthreads();
        if (c < 31) {
            double g1x = ge[s][c + 1][0], g1y = ge[s][c + 1][1];
            double q1x = gd[s][c + 1][0], q1y = gd[s][c + 1][1];
            if (c == 0) {
                Sed[s][0] = invmd[0] * (gx * g1x + gy * g1y);
                Ked[s][0] = invmd[0] * ((gdx * g1x + gdy * g1y) - (gx * q1x + gy * q1y));
            } else {
                Sed[s][c] = -invmd[c] * (gx * g1x + gy * g1y);
                Ked[s][c] =  invmd[c] * ((gx * q1x + gy * q1y) - (gdx * g1x + gdy * g1y));
            }
        }
    }
    __syncthreads();

    // ---- fp64 Thomas: factor S, solve S X1 = b0 (in place in b0d) ----
    if (tid < SPB) {
        int s = tid;
        double d = Sdd[s][0];
        if (d == 0.0) d = 1e-300;
        dinv[s][0] = 1.0 / d;
        double y = b0d[s][0];
        for (int c = 1; c < NP; ++c) {
            double e = Sed[s][c - 1];
            double w = e * dinv[s][c - 1];
            wfac[s][c - 1] = w;
            d = Sdd[s][c] - w * e;
            if (d == 0.0) d = 1e-300;
            dinv[s][c] = 1.0 / d;
            y = b0d[s][c] - w * y;
            b0d[s][c] = y;
        }
        double x = b0d[s][31] * dinv[s][31];
        b0d[s][31] = x;
        for (int c = 30; c >= 0; --c) {
            x = (b0d[s][c] - Sed[s][c] * x) * dinv[s][c];
            b0d[s][c] = x;
        }
    }
    __syncthreads();

    // ---- rhs2 = K X1 - b1 (in place in b1d) ----
    {
        int c = tid & 31, s = tid >> 5;
        double kx = 0.0;
        if (c < 31) kx += Ked[s][c] * b0d[s][c + 1];
        if (c > 0)  kx -= Ked[s][c - 1] * b0d[s][c - 1];
        b1d[s][c] = kx - b1d[s][c];
    }
    __syncthreads();

    // ---- solve S X0 = rhs2 with stored factors (in place in b1d) ----
    if (tid < SPB) {
        int s = tid;
        double y = b1d[s][0];
        for (int c = 1; c < NP; ++c) {
            y = b1d[s][c] - wfac[s][c - 1] * y;
            b1d[s][c] = y;
        }
        double x = b1d[s][31] * dinv[s][31];
        b1d[s][31] = x;
        for (int c = 30; c >= 0; --c) {
            x = (b1d[s][c] - Sed[s][c] * x) * dinv[s][c];
            b1d[s][c] = x;
        }
    }
    __syncthreads();

    // ---- output: [v - M^-1 G X1 ; -g + G X0 + Gdot X1]   (X1=b0d, X0=b1d) ----
    float* ob = out + sbase * ZD;
    #pragma unroll
    for (int k = 0; k < 4; ++k) {
        int e = k * NTH + tid;
        int s = e >> 7, idx = e & 127;
        int j = idx & 63;
        int n = j >> 1, d = j & 1;
        float res;
        if (idx < 64) {
            double Gx1 = (n == 0) ? (double)ge[s][0][d] * b0d[s][0]
                                  : -(double)ge[s][n][d] * b0d[s][n];
            if (n < 31) Gx1 += (double)ge[s][n + 1][d] * b0d[s][n + 1];
            res = (float)((double)vsh[j][s] - invmd[n] * Gx1);
        } else {
            double Gx0 = (n == 0) ? (double)ge[s][0][d] * b1d[s][0]
                                  : -(double)ge[s][n][d] * b1d[s][n];
            if (n < 31) Gx0 += (double)ge[s][n + 1][d] * b1d[s][n + 1];
            double Gd1 = (n == 0) ? (double)gd[s][0][d] * b0d[s][0]
                                  : -(double)gd[s][n][d] * b0d[s][n];
            if (n < 31) Gd1 += (double)gd[s][n + 1][d] * b0d[s][n + 1];
            res = (float)(-(double)gsh[j][s] + Gx0 + Gd1);
        }
        ob[e] = res;
    }
}

extern "C" void kernel_launch(void* const* d_in, const int* in_sizes, int n_in,
                              void* d_out, int out_size, void* d_ws, size_t ws_size,
                              hipStream_t stream) {
    const float* z  = (const float*)d_in[1];
    const float* mp = (const float*)d_in[2];
    const float* W0 = (const float*)d_in[3];
    const float* B0 = (const float*)d_in[4];
    const float* W1 = (const float*)d_in[5];
    const float* B1 = (const float*)d_in[6];
    const float* W2 = (const float*)d_in[7];
    const float* B2 = (const float*)d_in[8];
    const float* W3 = (const float*)d_in[9];

    short* P = (short*)d_ws;   // 294912 bf16 elements = 576 KB packed weights

    prep_pack<<<144, 256, 0, stream>>>(W0, W1, W2, P);
    chnn_main<<<NBLK, NTH, 0, stream>>>(z, mp, B0, B1, B2, W3, P, (float*)d_out);
}